// Round 12
// baseline (260.812 us; speedup 1.0000x reference)
//
#include <hip/hip_runtime.h>
#include <hip/hip_bf16.h>
#include <math.h>

#define QLEN 1024
#define MLEN 1024
#define KLEN 2048
#define BSZ 4
#define NH 8
#define DH 64
#define DM 512
#define SCALE 0.125f
#define LN_EPS 1e-5f

#define RK_ROWS 2112   // KLEN + 64 pad rows (pad = harness poison, finite bf16, masked)

typedef __attribute__((ext_vector_type(8))) short short8;   // 8 bf16 (4 VGPRs)
typedef __attribute__((ext_vector_type(4))) float float4_;  // MFMA C/D

#define GLB(p) ((const __attribute__((address_space(1))) void*)(p))
#define LDSP(p) ((__attribute__((address_space(3))) void*)(p))

__device__ inline ushort to_bf16(float x) {
  __hip_bfloat16 h = __float2bfloat16(x);
  return *reinterpret_cast<ushort*>(&h);
}

// 16-lane (row) reductions on the VALU pipe via DPP.
__device__ inline float row_max16(float v) {
  int x = __builtin_bit_cast(int, v);
  v = fmaxf(v, __builtin_bit_cast(float, __builtin_amdgcn_update_dpp(x, x, 0xB1, 0xF, 0xF, false)));
  x = __builtin_bit_cast(int, v);
  v = fmaxf(v, __builtin_bit_cast(float, __builtin_amdgcn_update_dpp(x, x, 0x4E, 0xF, 0xF, false)));
  x = __builtin_bit_cast(int, v);
  v = fmaxf(v, __builtin_bit_cast(float, __builtin_amdgcn_update_dpp(x, x, 0x124, 0xF, 0xF, false)));
  x = __builtin_bit_cast(int, v);
  v = fmaxf(v, __builtin_bit_cast(float, __builtin_amdgcn_update_dpp(x, x, 0x128, 0xF, 0xF, false)));
  return v;
}
__device__ inline float row_sum16(float v) {
  int x = __builtin_bit_cast(int, v);
  v += __builtin_bit_cast(float, __builtin_amdgcn_update_dpp(x, x, 0xB1, 0xF, 0xF, false));
  x = __builtin_bit_cast(int, v);
  v += __builtin_bit_cast(float, __builtin_amdgcn_update_dpp(x, x, 0x4E, 0xF, 0xF, false));
  x = __builtin_bit_cast(int, v);
  v += __builtin_bit_cast(float, __builtin_amdgcn_update_dpp(x, x, 0x124, 0xF, 0xF, false));
  x = __builtin_bit_cast(int, v);
  v += __builtin_bit_cast(float, __builtin_amdgcn_update_dpp(x, x, 0x128, 0xF, 0xF, false));
  return v;
}

// ---------------------------------------------------------------------------
// Fused weight transpose+convert: z selects {Wq, Wkv, Wr, Wo}.
// ---------------------------------------------------------------------------
__global__ __launch_bounds__(256) void wtrans_all(
    const float* __restrict__ Wq, const float* __restrict__ Wkv,
    const float* __restrict__ Wr, const float* __restrict__ Wo,
    ushort* __restrict__ WqT, ushort* __restrict__ WkvT,
    ushort* __restrict__ WrT, ushort* __restrict__ WoT) {
  __shared__ ushort tile[32][33];
  const int z = blockIdx.z;
  const float* W;
  ushort* WT;
  int N;
  if (z == 0)      { W = Wq;  WT = WqT;  N = DM; }
  else if (z == 1) { W = Wkv; WT = WkvT; N = 2 * DM; }
  else if (z == 2) { W = Wr;  WT = WrT;  N = DM; }
  else             { W = Wo;  WT = WoT;  N = DM; }
  const int k0 = blockIdx.x * 32, n0 = blockIdx.y * 32;
  if (n0 >= N) return;
  const int tid = threadIdx.x;
#pragma unroll
  for (int it = 0; it < 4; ++it) {
    int idx = tid + it * 256;
    int r = idx >> 5, c = idx & 31;
    tile[r][c] = to_bf16(W[(size_t)(k0 + r) * N + n0 + c]);
  }
  __syncthreads();
#pragma unroll
  for (int it = 0; it < 4; ++it) {
    int idx = tid + it * 256;
    int r = idx >> 5, c = idx & 31;
    WT[(size_t)(n0 + r) * DM + k0 + c] = tile[c][r];
  }
}

// ---------------------------------------------------------------------------
// Merged MFMA projection GEMM (single dispatch, 704 blocks, 1D decode).
// Swapped operands: acc = mfma(bf, af, acc) -> lane holds C[mm=..+l16][nn=
// ..+quad*4+reg] (4 consecutive cols) -> vector stores.
//  mode 0 (128 blk): w @ Wq    -> qw/qr (+biases), ushort4 stores
//  mode 1 (512 blk): cat @ Wkv -> k2 ushort4; v2 via LDS transpose -> uint4
//  mode 2 ( 64 blk): r @ Wr    -> rk2 XOR-swizzled, ushort4
// ---------------------------------------------------------------------------
__global__ __launch_bounds__(256) void proj_all(
    const float* __restrict__ w, const float* __restrict__ mems,
    const float* __restrict__ r,
    const ushort* __restrict__ WqT, const ushort* __restrict__ WkvT,
    const ushort* __restrict__ WrT,
    const float* __restrict__ bias0, const float* __restrict__ bias1,
    ushort* __restrict__ qw, ushort* __restrict__ qr,
    ushort* __restrict__ k2, ushort* __restrict__ v2,
    ushort* __restrict__ rk2) {
  __shared__ ushort smem[128 * 68];   // As(128x32) | Bs(128x32); epilogue scratch
  ushort* As = smem;
  ushort* Bs = smem + 128 * 32;
  const int tid = threadIdx.x;
  int mode, bx, by;
  {
    int id = blockIdx.x;
    if (id < 128)      { mode = 0; bx = id >> 2;         by = id & 3; }
    else if (id < 640) { mode = 1; bx = (id - 128) >> 3; by = (id - 128) & 7; }
    else               { mode = 2; bx = (id - 640) >> 2; by = (id - 640) & 3; }
  }
  const int m0 = bx * 128, n0 = by * 128;
  const int wv = tid >> 6, lane = tid & 63;
  const int wm = wv >> 1, wn = wv & 1;
  const int l16 = lane & 15, quad = lane >> 4;

  const int arow = tid >> 1;
  const int acol = (tid & 1) * 16;
  const float* asrc;
  {
    int m = m0 + arow;
    if (mode == 2) asrc = r + (size_t)m * DM;
    else asrc = (m < QLEN * BSZ) ? w + (size_t)m * DM
                                 : mems + (size_t)(m - QLEN * BSZ) * DM;
    asrc += acol;
  }
  const ushort* BT = (mode == 0) ? WqT : (mode == 1) ? WkvT : WrT;
  const ushort* bsrc = BT + (size_t)(n0 + arow) * DM + acol;

  float4_ acc[4][4];
#pragma unroll
  for (int a = 0; a < 4; ++a)
#pragma unroll
    for (int b = 0; b < 4; ++b) acc[a][b] = float4_{0.f, 0.f, 0.f, 0.f};

  for (int k0 = 0; k0 < DM; k0 += 32) {
    float4 a0 = *reinterpret_cast<const float4*>(asrc + k0);
    float4 a1 = *reinterpret_cast<const float4*>(asrc + k0 + 4);
    float4 a2 = *reinterpret_cast<const float4*>(asrc + k0 + 8);
    float4 a3 = *reinterpret_cast<const float4*>(asrc + k0 + 12);
    ushort4 u0, u1, u2, u3;
    u0.x = to_bf16(a0.x); u0.y = to_bf16(a0.y); u0.z = to_bf16(a0.z); u0.w = to_bf16(a0.w);
    u1.x = to_bf16(a1.x); u1.y = to_bf16(a1.y); u1.z = to_bf16(a1.z); u1.w = to_bf16(a1.w);
    u2.x = to_bf16(a2.x); u2.y = to_bf16(a2.y); u2.z = to_bf16(a2.z); u2.w = to_bf16(a2.w);
    u3.x = to_bf16(a3.x); u3.y = to_bf16(a3.y); u3.z = to_bf16(a3.z); u3.w = to_bf16(a3.w);
    *reinterpret_cast<ushort4*>(&As[arow * 32 + acol]) = u0;
    *reinterpret_cast<ushort4*>(&As[arow * 32 + acol + 4]) = u1;
    *reinterpret_cast<ushort4*>(&As[arow * 32 + acol + 8]) = u2;
    *reinterpret_cast<ushort4*>(&As[arow * 32 + acol + 12]) = u3;
    *reinterpret_cast<uint4*>(&Bs[arow * 32 + acol]) =
        *reinterpret_cast<const uint4*>(bsrc + k0);
    *reinterpret_cast<uint4*>(&Bs[arow * 32 + acol + 8]) =
        *reinterpret_cast<const uint4*>(bsrc + k0 + 8);
    __syncthreads();
    short8 af[4], bf[4];
#pragma unroll
    for (int f = 0; f < 4; ++f) {
      af[f] = *reinterpret_cast<const short8*>(&As[(wm * 64 + f * 16 + l16) * 32 + quad * 8]);
      bf[f] = *reinterpret_cast<const short8*>(&Bs[(wn * 64 + f * 16 + l16) * 32 + quad * 8]);
    }
#pragma unroll
    for (int fm = 0; fm < 4; ++fm)
#pragma unroll
      for (int fn = 0; fn < 4; ++fn)
        acc[fm][fn] = __builtin_amdgcn_mfma_f32_16x16x32_bf16(bf[fn], af[fm], acc[fm][fn], 0, 0, 0);
    __syncthreads();
  }

  if (mode == 1 && n0 >= DM) {
    // ---- V half: LDS transpose -> coalesced uint4 stores into v2 ----
    // Writer: y[row=mm_local][col(strip)=d] at smem[row*68 + (col4^(row>>5))*4 + col&3]
    const int jb = bx;
    const int hd0 = (n0 - DM) >> 6;
#pragma unroll
    for (int pass = 0; pass < 2; ++pass) {
      if (wn == pass) {
#pragma unroll
        for (int fm = 0; fm < 4; ++fm)
#pragma unroll
          for (int fn = 0; fn < 4; ++fn) {
            int row = wm * 64 + fm * 16 + l16;
            int col4 = fn * 4 + quad;          // col = col4*4
            int c4s = col4 ^ (row >> 5);
            const float4_ a = acc[fm][fn];
            ushort4 o;
            o.x = to_bf16(a[0]); o.y = to_bf16(a[1]);
            o.z = to_bf16(a[2]); o.w = to_bf16(a[3]);
            *reinterpret_cast<ushort4*>(&smem[row * 68 + c4s * 4]) = o;
          }
      }
      __syncthreads();
      // Reader: b = tid>>6; per s: tile=s, lane2=tid&63, d=s*16+(tid&15),
      // octet=(tid>>4)&3, row=(octet*8+u)*4+b
      {
        const int b = tid >> 6;
        const int lane2 = tid & 63;
        const int octet = (lane2 >> 4) & 3;
        const int bn = b * NH + hd0 + pass;
        ushort* chunk = v2 + (((size_t)bn * 64 + jb) * 4) * 512;
#pragma unroll
        for (int s = 0; s < 4; ++s) {
          const int d = s * 16 + (lane2 & 15);
          const int c4s = (d >> 2) ^ octet;
          const int cl = c4s * 4 + (d & 3);
          ushort val[8];
#pragma unroll
          for (int u = 0; u < 8; ++u)
            val[u] = smem[((octet * 8 + u) * 4 + b) * 68 + cl];
          *reinterpret_cast<uint4*>(chunk + (size_t)s * 512 + lane2 * 8) =
              *reinterpret_cast<uint4*>(val);
        }
      }
      __syncthreads();
    }
    return;
  }

#pragma unroll
  for (int fm = 0; fm < 4; ++fm) {
#pragma unroll
    for (int fn = 0; fn < 4; ++fn) {
      const int mm = m0 + wm * 64 + fm * 16 + l16;
      const int nnb = n0 + wn * 64 + fn * 16 + quad * 4;
      const float4_ a = acc[fm][fn];
      if (mode == 0) {
        float4 b0v = *reinterpret_cast<const float4*>(bias0 + nnb);
        float4 b1v = *reinterpret_cast<const float4*>(bias1 + nnb);
        int i = mm >> 2, b = mm & 3;
        int hd = nnb >> 6, d0 = nnb & 63;
        size_t idx = (((size_t)(b * NH + hd)) * QLEN + i) * DH + d0;
        ushort4 o0, o1;
        o0.x = to_bf16(a[0] + b0v.x); o0.y = to_bf16(a[1] + b0v.y);
        o0.z = to_bf16(a[2] + b0v.z); o0.w = to_bf16(a[3] + b0v.w);
        o1.x = to_bf16(a[0] + b1v.x); o1.y = to_bf16(a[1] + b1v.y);
        o1.z = to_bf16(a[2] + b1v.z); o1.w = to_bf16(a[3] + b1v.w);
        *reinterpret_cast<ushort4*>(qw + idx) = o0;
        *reinterpret_cast<ushort4*>(qr + idx) = o1;
      } else if (mode == 1) {
        // K half only (V handled above)
        int pos = mm >> 2, b = mm & 3;
        int jb = pos >> 5, jj = pos & 31;
        int hd = nnb >> 6, d = nnb & 63;
        int bn = b * NH + hd;
        int tile = ((jj >> 4) << 1) | (d >> 5);
        int lane2 = (((d >> 3) & 3) << 4) | (jj & 15);
        ushort4 o;
        o.x = to_bf16(a[0]); o.y = to_bf16(a[1]);
        o.z = to_bf16(a[2]); o.w = to_bf16(a[3]);
        *reinterpret_cast<ushort4*>(
            k2 + ((((size_t)bn * 64 + jb) * 4 + tile) * 64 + lane2) * 8 + (d & 7)) = o;
      } else {
        int t = mm;
        int hd = nnb >> 6, d = nnb & 63;
        int cb = d >> 3;
        int dcol = ((cb ^ (t & 7)) << 3) | (d & 7);
        ushort4 o;
        o.x = to_bf16(a[0]); o.y = to_bf16(a[1]);
        o.z = to_bf16(a[2]); o.w = to_bf16(a[3]);
        *reinterpret_cast<ushort4*>(
            rk2 + ((size_t)hd * RK_ROWS + t) * DH + dcol) = o;
      }
    }
  }
}

// ---------------------------------------------------------------------------
// Fused output GEMM + residual LayerNorm. Block = 16 rows x 512 cols;
// 4 waves split cols (128 each). Swapped operands -> float4 out stores.
// Cross-wave LN reduction via LDS. No y round-trip.
// ---------------------------------------------------------------------------
__global__ __launch_bounds__(256) void out_ln_mfma(
    const ushort* __restrict__ avbf, const ushort* __restrict__ WoT,
    const float* __restrict__ wres, const float* __restrict__ g,
    const float* __restrict__ bb, float* __restrict__ out) {
  __shared__ ushort As[16 * 32];
  __shared__ float red[2][4][16];
  const int tid = threadIdx.x;
  const int wv = tid >> 6, lane = tid & 63;
  const int l16 = lane & 15, quad = lane >> 4;
  const int m0 = blockIdx.x * 16;

  float4_ acc[8];
#pragma unroll
  for (int f = 0; f < 8; ++f) acc[f] = float4_{0.f, 0.f, 0.f, 0.f};

  for (int k0 = 0; k0 < DM; k0 += 32) {
    if (tid < 128)
      *reinterpret_cast<ushort4*>(&As[(tid >> 3) * 32 + (tid & 7) * 4]) =
          *reinterpret_cast<const ushort4*>(
              avbf + (size_t)(m0 + (tid >> 3)) * DM + k0 + (tid & 7) * 4);
    __syncthreads();
    short8 af = *reinterpret_cast<const short8*>(&As[l16 * 32 + quad * 8]);
#pragma unroll
    for (int fn = 0; fn < 8; ++fn) {
      short8 bf = *reinterpret_cast<const short8*>(
          WoT + (size_t)(wv * 128 + fn * 16 + l16) * DM + k0 + quad * 8);
      acc[fn] = __builtin_amdgcn_mfma_f32_16x16x32_bf16(bf, af, acc[fn], 0, 0, 0);
    }
    __syncthreads();
  }

  const int row = m0 + l16;
  float s = 0.f, ss = 0.f;
  float4 xv[8];
#pragma unroll
  for (int fn = 0; fn < 8; ++fn) {
    int ncol = wv * 128 + fn * 16 + quad * 4;
    float4 wv4 = *reinterpret_cast<const float4*>(wres + (size_t)row * DM + ncol);
    float4 x;
    x.x = acc[fn][0] + wv4.x; x.y = acc[fn][1] + wv4.y;
    x.z = acc[fn][2] + wv4.z; x.w = acc[fn][3] + wv4.w;
    xv[fn] = x;
    s += x.x + x.y + x.z + x.w;
    ss += x.x * x.x + x.y * x.y + x.z * x.z + x.w * x.w;
  }
  s += __shfl_xor(s, 16, 64);  s += __shfl_xor(s, 32, 64);
  ss += __shfl_xor(ss, 16, 64); ss += __shfl_xor(ss, 32, 64);
  if (quad == 0) { red[0][wv][l16] = s; red[1][wv][l16] = ss; }
  __syncthreads();
  float S = red[0][0][l16] + red[0][1][l16] + red[0][2][l16] + red[0][3][l16];
  float SS = red[1][0][l16] + red[1][1][l16] + red[1][2][l16] + red[1][3][l16];
  float mu = S * (1.f / DM);
  float var = SS * (1.f / DM) - mu * mu;
  float rstd = rsqrtf(var + LN_EPS);
#pragma unroll
  for (int fn = 0; fn < 8; ++fn) {
    int ncol = wv * 128 + fn * 16 + quad * 4;
    float4 g4 = *reinterpret_cast<const float4*>(g + ncol);
    float4 b4 = *reinterpret_cast<const float4*>(bb + ncol);
    float4 o;
    o.x = (xv[fn].x - mu) * rstd * g4.x + b4.x;
    o.y = (xv[fn].y - mu) * rstd * g4.y + b4.y;
    o.z = (xv[fn].z - mu) * rstd * g4.z + b4.z;
    o.w = (xv[fn].w - mu) * rstd * g4.w + b4.w;
    *reinterpret_cast<float4*>(out + (size_t)row * DM + ncol) = o;
  }
}

// ---------------------------------------------------------------------------
// MFMA flash attention (FROZEN from r9 — matched prediction):
//  64 Q rows/block (4 waves), shared 32-key chunks, double-buffered
//  global_load_lds staging, vmcnt(5), raw barriers, no cross-wave combine.
// ---------------------------------------------------------------------------
__global__ __launch_bounds__(256) void attn_mfma(
    const ushort* __restrict__ qw, const ushort* __restrict__ qr,
    const ushort* __restrict__ k2, const ushort* __restrict__ v2,
    const ushort* __restrict__ rk2, ushort* __restrict__ avbf) {
  const int i0b = (gridDim.x - 1 - blockIdx.x) * 64;  // longest blocks first
  const int n = blockIdx.y, b = blockIdx.z;
  const int bn = b * NH + n;
  const int tid = threadIdx.x;
  const int wv = tid >> 6, lane = tid & 63;
  const int l16 = lane & 15, quad = lane >> 4;
  const int i0w = i0b + wv * 16;

  __shared__ ushort stage[2][20 * 512];   // K 4x512 | V 4x512 | R 96x64
  __shared__ float Dlds[4][16 * 66];
  __shared__ ushort Plds[4][16 * 32];
  float* __restrict__ Dw = Dlds[wv];
  ushort* __restrict__ Pw = Plds[wv];

  const ushort* __restrict__ k2b = k2 + (size_t)bn * (64 * 4 * 512);
  const ushort* __restrict__ v2b = v2 + (size_t)bn * (64 * 4 * 512);
  const ushort* __restrict__ rk2n = rk2 + (size_t)n * RK_ROWS * DH;

  const int nIter = (i0b + 63 + MLEN) / 32 + 1;

  short8 aqw0, aqw1, aqr0, aqr1;
  {
    const ushort* qwp = qw + (((size_t)bn * QLEN) + i0w + l16) * DH + quad * 8;
    const ushort* qrp = qr + (((size_t)bn * QLEN) + i0w + l16) * DH + quad * 8;
    aqw0 = *(const short8*)(qwp);
    aqw1 = *(const short8*)(qwp + 32);
    aqr0 = *(const short8*)(qrp);
    aqr1 = *(const short8*)(qrp + 32);
  }

  auto issue_dma = [&](int jb, int buf) {
    const int tbase = jb * 32 - i0b + 960;
#pragma unroll
    for (int s = 0; s < 5; ++s) {
      const int m = wv + s * 4;
      const ushort* g;
      if (m < 8) {
        const ushort* base = (m < 4) ? k2b : v2b;
        g = base + ((size_t)jb * 4 + (m & 3)) * 512 + lane * 8;
      } else {
        int tr = tbase + (m - 8) * 8 + (lane >> 3);
        g = rk2n + (size_t)tr * DH + (lane & 7) * 8;
      }
      __builtin_amdgcn_global_load_lds(GLB(g), LDSP(&stage[buf][m * 512]), 16, 0, 0);
    }
  };

  float4_ O[4];
#pragma unroll
  for (int t = 0; t < 4; ++t) O[t] = float4_{0.f, 0.f, 0.f, 0.f};
  float mrow[4] = {-INFINITY, -INFINITY, -INFINITY, -INFINITY};
  float lpart[4] = {0.f, 0.f, 0.f, 0.f};
  const float SL2E = SCALE * 1.44269504088896f;
  const int rbase = 48 - 16 * wv;
  const int sw = (l16 & 7);

  issue_dma(0, 0);
  issue_dma(1 < nIter ? 1 : 0, 1);

  for (int k = 0; k < nIter; ++k) {
    __builtin_amdgcn_s_waitcnt(0x0F75);  // vmcnt<=5
    __builtin_amdgcn_sched_barrier(0);
    __builtin_amdgcn_s_barrier();
    __builtin_amdgcn_sched_barrier(0);
    const ushort* sb = stage[k & 1];
    const int j0 = k * 32;

    float4_ ac[2];
#pragma unroll
    for (int h = 0; h < 2; ++h) {
      short8 b0 = *(const short8*)(sb + (h * 2 + 0) * 512 + lane * 8);
      short8 b1 = *(const short8*)(sb + (h * 2 + 1) * 512 + lane * 8);
      float4_ c = {0.f, 0.f, 0.f, 0.f};
      c = __builtin_amdgcn_mfma_f32_16x16x32_bf16(aqw0, b0, c, 0, 0, 0);
      c = __builtin_amdgcn_mfma_f32_16x16x32_bf16(aqw1, b1, c, 0, 0, 0);
      ac[h] = c;
    }
#pragma unroll
    for (int tt = 0; tt < 3; ++tt) {
      int rowLoc = rbase + tt * 16 + l16;
      const ushort* rrow = sb + 4096 + rowLoc * 64;
      short8 b0 = *(const short8*)(rrow + (((0 + quad) ^ sw) << 3));
      short8 b1 = *(const short8*)(rrow + (((4 + quad) ^ sw) << 3));
      float4_ d = {0.f, 0.f, 0.f, 0.f};
      d = __builtin_amdgcn_mfma_f32_16x16x32_bf16(aqr0, b0, d, 0, 0, 0);
      d = __builtin_amdgcn_mfma_f32_16x16x32_bf16(aqr1, b1, d, 0, 0, 0);
#pragma unroll
      for (int rg = 0; rg < 4; ++rg) {
        int row = quad * 4 + rg;
        Dw[row * 66 + tt * 16 + l16 + row] = d[rg];
      }
    }
    float s[2][4];
#pragma unroll
    for (int half = 0; half < 2; ++half) {
#pragma unroll
      for (int rg = 0; rg < 4; ++rg) {
        int row = quad * 4 + rg;
        int jloc = half * 16 + l16;
        float bd = Dw[row * 66 + jloc + 15];
        float sv = (ac[half][rg] + bd) * SL2E;
        s[half][rg] = (j0 + jloc > i0w + row + MLEN) ? -INFINITY : sv;
      }
    }
#pragma unroll
    for (int rg = 0; rg < 4; ++rg) {
      float mx = row_max16(fmaxf(s[0][rg], s[1][rg]));
      float mn = fmaxf(mrow[rg], mx);
      float alpha = __builtin_amdgcn_exp2f(mrow[rg] - mn);
      float p0 = __builtin_amdgcn_exp2f(s[0][rg] - mn);
      float p1 = __builtin_amdgcn_exp2f(s[1][rg] - mn);
      lpart[rg] = lpart[rg] * alpha + (p0 + p1);
      mrow[rg] = mn;
#pragma unroll
      for (int t = 0; t < 4; ++t) O[t][rg] *= alpha;
      int row = quad * 4 + rg;
      int idx0 = (l16 >> 3) * 128 + row * 8 + (l16 & 7);
      Pw[idx0] = to_bf16(p0);
      Pw[idx0 + 256] = to_bf16(p1);
    }
    short8 pfrag = *(const short8*)(Pw + lane * 8);
#pragma unroll
    for (int t = 0; t < 4; ++t) {
      short8 vfrag = *(const short8*)(sb + (4 + t) * 512 + lane * 8);
      O[t] = __builtin_amdgcn_mfma_f32_16x16x32_bf16(pfrag, vfrag, O[t], 0, 0, 0);
    }

    __builtin_amdgcn_sched_barrier(0);
    __builtin_amdgcn_s_barrier();
    __builtin_amdgcn_sched_barrier(0);
    int jn = k + 2;
    if (jn > nIter - 1) jn = nIter - 1;
    issue_dma(jn, k & 1);
  }

  float inv[4];
#pragma unroll
  for (int rg = 0; rg < 4; ++rg) inv[rg] = 1.f / row_sum16(lpart[rg]);
#pragma unroll
  for (int t = 0; t < 4; ++t)
#pragma unroll
    for (int rg = 0; rg < 4; ++rg) {
      int row = quad * 4 + rg;
      avbf[((size_t)(i0w + row) * BSZ + b) * DM + n * DH + t * 16 + l16] =
          to_bf16(O[t][rg] * inv[rg]);
    }
}

extern "C" void kernel_launch(void* const* d_in, const int* in_sizes, int n_in,
                              void* d_out, int out_size, void* d_ws, size_t ws_size,
                              hipStream_t stream) {
  const float* w    = (const float*)d_in[0];
  const float* r    = (const float*)d_in[1];
  const float* rwb  = (const float*)d_in[2];
  const float* rrb  = (const float*)d_in[3];
  const float* mems = (const float*)d_in[4];
  const float* Wq   = (const float*)d_in[5];
  const float* Wkv  = (const float*)d_in[6];
  const float* Wr   = (const float*)d_in[7];
  const float* Wo   = (const float*)d_in[8];
  const float* ln_g = (const float*)d_in[9];
  const float* ln_b = (const float*)d_in[10];
  float* out = (float*)d_out;

  char* p = (char*)d_ws;
  auto alloc = [&](size_t bytes) {
    char* q = p;
    p += (bytes + 255) & ~(size_t)255;
    return q;
  };
  ushort* WqT   = (ushort*)alloc((size_t)DM * DM * 2);
  ushort* WkvT  = (ushort*)alloc((size_t)2 * DM * DM * 2);
  ushort* WrT   = (ushort*)alloc((size_t)DM * DM * 2);
  ushort* WoT   = (ushort*)alloc((size_t)DM * DM * 2);
  ushort* qw    = (ushort*)alloc((size_t)BSZ * NH * QLEN * DH * 2);     // 4 MB
  ushort* qr    = (ushort*)alloc((size_t)BSZ * NH * QLEN * DH * 2);     // 4 MB
  ushort* k2    = (ushort*)alloc((size_t)BSZ * NH * 64 * 4 * 512 * 2);  // 8 MB
  ushort* v2    = (ushort*)alloc((size_t)BSZ * NH * 64 * 4 * 512 * 2);  // 8 MB
  ushort* rk2   = (ushort*)alloc((size_t)NH * RK_ROWS * DH * 2);        // ~2.1 MB
  ushort* avbf  = (ushort*)alloc((size_t)QLEN * BSZ * DM * 2);          // 4 MB

  wtrans_all<<<dim3(16, 32, 4), dim3(256), 0, stream>>>(
      Wq, Wkv, Wr, Wo, WqT, WkvT, WrT, WoT);
  proj_all<<<dim3(704), dim3(256), 0, stream>>>(
      w, mems, r, WqT, WkvT, WrT, rwb, rrb, qw, qr, k2, v2, rk2);
  attn_mfma<<<dim3(QLEN / 64, NH, BSZ), dim3(256), 0, stream>>>(qw, qr, k2, v2, rk2, avbf);
  out_ln_mfma<<<dim3(QLEN * BSZ / 16), dim3(256), 0, stream>>>(
      avbf, WoT, w, ln_g, ln_b, out);
}